// Round 1
// baseline (3834.287 us; speedup 1.0000x reference)
//
#include <hip/hip_runtime.h>
#include <hip/hip_bf16.h>

// ---------------- constants ----------------
#define L1X   1500   // raw sequence length
#define L1P   751    // pool1 length
#define C1    64
#define L2P   377    // pool2 length
#define C2    128
#define L3P   191    // pool3 length
#define C3    128
#define FEATK 24448  // C3*L3P
#define D2    256
#define HIDN  128

// =====================================================================
// K2: fused conv1(+bn+relu+pool) recompute  ->  conv2+bn2+relu+pool
// grid: rows_in_chunk * 24 tiles, block 256
// =====================================================================
__global__ __launch_bounds__(256)
void k_conv12(const float* __restrict__ X, const float* __restrict__ w1,
              const float* __restrict__ bn1, const float* __restrict__ w2,
              const float* __restrict__ bn2, float* __restrict__ pool2,
              int b_off)
{
    const int blk  = blockIdx.x;
    const int b    = b_off + blk / 24;
    const int i0   = (blk % 24) * 16;

    __shared__ float xrow[L1X];
    __shared__ float t1[C1 * 34];

    for (int e = threadIdx.x; e < L1X; e += 256) xrow[e] = X[(size_t)b * L1X + e];
    __syncthreads();

    // pool1 tile: t in [tb, tb+33]
    const int tb = 2 * i0 - 3;
    for (int e = threadIdx.x; e < C1 * 34; e += 256) {
        int c = e / 34, j = e - c * 34;
        int t = tb + j;
        float val = 0.f;
        if (t >= 0 && t < L1P) {
            float wk0 = w1[c*3+0], wk1 = w1[c*3+1], wk2 = w1[c*3+2];
            float s    = bn1[c] * rsqrtf(bn1[192+c] + 1e-5f);
            float bias = bn1[64+c] - bn1[128+c] * s;
            float v0 = 0.f, v1 = 0.f;
            if (t >= 1) {               // conv pos l = 2t-1  (reads x[2t-2..2t])
                int l = 2*t - 1;
                float x2 = (l+1 < L1X) ? xrow[l+1] : 0.f;
                float cv = wk0*xrow[l-1] + wk1*xrow[l] + wk2*x2;
                v0 = fmaxf(cv*s + bias, 0.f);
            }
            if (t <= 749) {             // conv pos l = 2t    (reads x[2t-1..2t+1])
                int l = 2*t;
                float x0 = (l-1 >= 0) ? xrow[l-1] : 0.f;
                float cv = wk0*x0 + wk1*xrow[l] + wk2*xrow[l+1];
                v1 = fmaxf(cv*s + bias, 0.f);
            }
            val = fmaxf(v0, v1);
        }
        t1[c*34 + j] = val;
    }
    __syncthreads();

    const int c    = threadIdx.x & 127;   // out-channel
    const int grp  = threadIdx.x >> 7;    // position group (0/1)
    const int lbase = 16 * grp;

    float acc0[8] = {0,0,0,0,0,0,0,0};
    float acc1[8] = {0,0,0,0,0,0,0,0};
    const float* Wc = w2 + c * (C1*3);

    for (int ic = 0; ic < C1; ++ic) {
        float xv[18];
        #pragma unroll
        for (int q = 0; q < 18; ++q) xv[q] = t1[ic*34 + lbase + q];
        #pragma unroll
        for (int k = 0; k < 3; ++k) {
            float w = Wc[ic*3 + k];
            #pragma unroll
            for (int j = 0; j < 8; ++j) {
                acc0[j] += w * xv[2*j + k];
                acc1[j] += w * xv[2*j + k + 1];
            }
        }
    }
    float s2 = bn2[c] * rsqrtf(bn2[384+c] + 1e-5f);
    float b2 = bn2[128+c] - bn2[256+c] * s2;
    #pragma unroll
    for (int j = 0; j < 8; ++j) {
        int i = i0 + grp*8 + j;
        if (i < L2P) {
            float v0 = (i >= 1) ? fmaxf(acc0[j]*s2 + b2, 0.f) : 0.f;
            float v1 = fmaxf(acc1[j]*s2 + b2, 0.f);
            pool2[((size_t)(b - b_off)*C2 + c)*L2P + i] = fmaxf(v0, v1);
        }
    }
}

// =====================================================================
// K3: conv3+bn3+relu+pool. grid: rows_in_chunk * 12 tiles, block 256
// =====================================================================
__global__ __launch_bounds__(256)
void k_conv3(const float* __restrict__ pool2, const float* __restrict__ w3,
             const float* __restrict__ bn3, float* __restrict__ pool3, int b_off)
{
    const int blk = blockIdx.x;
    const int bl  = blk / 12;             // local row in chunk
    const int b   = b_off + bl;           // global row
    const int i0  = (blk % 12) * 16;

    __shared__ float t2[C2 * 34];
    const int tb = 2*i0 - 4;
    for (int e = threadIdx.x; e < C2*34; e += 256) {
        int ic = e / 34, j = e - ic*34;
        int t = tb + j;
        t2[e] = (t >= 0 && t < L2P) ? pool2[((size_t)bl*C2 + ic)*L2P + t] : 0.f;
    }
    __syncthreads();

    const int c    = threadIdx.x & 127;
    const int grp  = threadIdx.x >> 7;
    const int lbase = 16 * grp;

    float acc0[8] = {0,0,0,0,0,0,0,0};
    float acc1[8] = {0,0,0,0,0,0,0,0};
    const float* Wc = w3 + c * (C2*3);

    for (int ic = 0; ic < C2; ++ic) {
        float xv[18];
        #pragma unroll
        for (int q = 0; q < 18; ++q) xv[q] = t2[ic*34 + lbase + q];
        #pragma unroll
        for (int k = 0; k < 3; ++k) {
            float w = Wc[ic*3 + k];
            #pragma unroll
            for (int j = 0; j < 8; ++j) {
                acc0[j] += w * xv[2*j + k];
                acc1[j] += w * xv[2*j + k + 1];
            }
        }
    }
    float s3 = bn3[c] * rsqrtf(bn3[384+c] + 1e-5f);
    float b3 = bn3[128+c] - bn3[256+c] * s3;
    #pragma unroll
    for (int j = 0; j < 8; ++j) {
        int i = i0 + grp*8 + j;
        if (i < L3P) {
            float v0 = (i >= 1) ? fmaxf(acc0[j]*s3 + b3, 0.f) : 0.f;
            float v1 = fmaxf(acc1[j]*s3 + b3, 0.f);
            pool3[((size_t)b*C3 + c)*L3P + i] = fmaxf(v0, v1);
        }
    }
}

// =====================================================================
// K4: a = BN(pool3.reshape(768,24448) @ map2_w + map2_b) + PE
// grid 96 (8 rows each), block 256 (one output column per thread)
// =====================================================================
__global__ __launch_bounds__(256)
void k_map2(const float* __restrict__ A, const float* __restrict__ W,
            const float* __restrict__ mb, const float* __restrict__ bn,
            float* __restrict__ out)
{
    const int row0 = blockIdx.x * 8;
    __shared__ float at[8][512];
    float acc[8] = {0,0,0,0,0,0,0,0};
    const int n = threadIdx.x;

    for (int f0 = 0; f0 < FEATK; f0 += 512) {
        int fmax = FEATK - f0; if (fmax > 512) fmax = 512;
        __syncthreads();
        for (int e = threadIdx.x; e < 8*512; e += 256) {
            int r = e >> 9, f = e & 511;
            at[r][f] = (f < fmax) ? A[(size_t)(row0 + r)*FEATK + f0 + f] : 0.f;
        }
        __syncthreads();
        for (int f = 0; f < fmax; ++f) {
            float wv = W[(size_t)(f0 + f)*D2 + n];
            #pragma unroll
            for (int r = 0; r < 8; ++r) acc[r] += at[r][f] * wv;
        }
    }

    float s    = bn[n] * rsqrtf(bn[768+n] + 1e-5f);
    float beta = bn[256+n];
    float mu   = bn[512+n];
    float bias = mb[n];
    int   jj   = n >> 1;
    float freq = expf((float)(2*jj) * (-4.605170185988092f / 256.f)); // -ln(100)/256
    #pragma unroll
    for (int r = 0; r < 8; ++r) {
        int row = row0 + r;
        int t = (row >> 2) % 6;
        float ang = (float)t * freq;
        float pe  = (n & 1) ? cosf(ang) : sinf(ang);
        out[(size_t)row*D2 + n] = (acc[r] + bias - mu)*s + beta + pe;
    }
}

// =====================================================================
// K5: MPNN block (win=2). one block per graph, block 256
// =====================================================================
__global__ __launch_bounds__(256)
void k_mpnn(const float* __restrict__ a_pe, const float* __restrict__ gw,
            const float* __restrict__ gb, const float* __restrict__ bnA,
            const float* __restrict__ tw, const float* __restrict__ tb_,
            const float* __restrict__ bnM, float* __restrict__ feats,
            int nw, int stride, int base)
{
    const int g  = blockIdx.x;
    const int b  = g / nw, wi = g % nw;
    const int tid = threadIdx.x;

    __shared__ float Xc[8][256];
    __shared__ float Xb[8][256];
    __shared__ float Fs[8][256];
    __shared__ float Adj[8][8];
    __shared__ float hsm[8][128];

    for (int e = tid; e < 2048; e += 256) {
        int nn = e >> 8, d = e & 255;
        int tt = nn >> 2, sn = nn & 3;
        float v = a_pe[(((size_t)(b*6) + (wi*stride + tt))*4 + sn)*D2 + d];
        Xc[nn][d] = v;
        float s = bnA[d] * rsqrtf(bnA[768+d] + 1e-5f);
        Xb[nn][d] = (v - bnA[512+d])*s + bnA[256+d];
    }
    __syncthreads();

    {   // f = Xc @ gw + gb
        const int d = tid;
        #pragma unroll
        for (int nn = 0; nn < 8; ++nn) {
            float acc = gb[d];
            for (int k = 0; k < 256; ++k) acc += Xc[nn][k] * gw[(size_t)k*D2 + d];
            Fs[nn][d] = acc;
        }
    }
    __syncthreads();

    if (tid < 64) {   // raw adjacency + diag suppress + leaky
        int nn = tid >> 3, m = tid & 7;
        float s = 0.f;
        for (int d = 0; d < 256; ++d) s += Fs[nn][d] * Fs[m][d];
        if (nn == m) s -= 1e8f;
        s = (s > 0.f) ? s : 0.01f*s;
        Adj[nn][m] = s;
    }
    __syncthreads();

    if (tid < 8) {    // softmax row + eye + decay mask
        int nn = tid;
        float mx = -1e30f;
        for (int m = 0; m < 8; ++m) mx = fmaxf(mx, Adj[nn][m]);
        float ex[8]; float sum = 0.f;
        for (int m = 0; m < 8; ++m) { ex[m] = expf(Adj[nn][m]-mx); sum += ex[m]; }
        float inv = 1.f / sum;
        for (int m = 0; m < 8; ++m) {
            float v = ex[m]*inv + ((nn==m) ? 1.f : 0.f);
            v *= ((nn>>2) == (m>>2)) ? 1.f : 0.7f;   // 0.7^|dt|, dt in {0,1}
            Adj[nn][m] = v;
        }
    }
    __syncthreads();

    {   // hmid = Adj @ Xb   (store into Fs, no longer needed)
        const int d = tid;
        float hm[8];
        #pragma unroll
        for (int nn = 0; nn < 8; ++nn) {
            float a = 0.f;
            #pragma unroll
            for (int m = 0; m < 8; ++m) a += Adj[nn][m] * Xb[m][d];
            hm[nn] = a;
        }
        #pragma unroll
        for (int nn = 0; nn < 8; ++nn) Fs[nn][d] = hm[nn];
    }
    __syncthreads();

    {   // h = leaky(BN(hmid @ tw + tb))
        const int o = tid & 127, half = tid >> 7;
        float ms  = bnM[o] * rsqrtf(bnM[384+o] + 1e-5f);
        float mbe = bnM[128+o], mmu = bnM[256+o];
        #pragma unroll
        for (int q = 0; q < 4; ++q) {
            int nn = half + 2*q;
            float acc = tb_[o];
            for (int d = 0; d < 256; ++d) acc += Fs[nn][d] * tw[(size_t)d*HIDN + o];
            float y = (acc - mmu)*ms + mbe;
            hsm[nn][o] = (y > 0.f) ? y : 0.01f*y;
        }
    }
    __syncthreads();

    for (int e = tid; e < 512; e += 256) {   // mean over window-time, write feats
        int sn = e >> 7, o = e & 127;
        feats[(size_t)b*4096 + base + (wi*4 + sn)*HIDN + o] =
            0.5f * (hsm[sn][o] + hsm[4+sn][o]);
    }
}

// =====================================================================
// K6: FC head, one block per batch row
// =====================================================================
__global__ __launch_bounds__(256)
void k_fc(const float* __restrict__ feats,
          const float* __restrict__ w1f, const float* __restrict__ b1f,
          const float* __restrict__ w2f, const float* __restrict__ b2f,
          const float* __restrict__ w3f, const float* __restrict__ b3f,
          const float* __restrict__ w4f, const float* __restrict__ b4f,
          float* __restrict__ out)
{
    const int b = blockIdx.x;
    __shared__ float row[4096];
    __shared__ float h1[256], h2[256], h3[128];
    for (int e = threadIdx.x; e < 4096; e += 256) row[e] = feats[(size_t)b*4096 + e];
    __syncthreads();
    const int n = threadIdx.x;
    {
        float acc = b1f[n];
        for (int f = 0; f < 4096; ++f) acc += row[f] * w1f[(size_t)f*256 + n];
        h1[n] = fmaxf(acc, 0.f);
    }
    __syncthreads();
    {
        float acc = b2f[n];
        for (int k = 0; k < 256; ++k) acc += h1[k] * w2f[(size_t)k*256 + n];
        h2[n] = fmaxf(acc, 0.f);
    }
    __syncthreads();
    if (n < 128) {
        float acc = b3f[n];
        for (int k = 0; k < 256; ++k) acc += h2[k] * w3f[(size_t)k*128 + n];
        h3[n] = fmaxf(acc, 0.f);
    }
    __syncthreads();
    if (n < 5) {
        float acc = b4f[n];
        for (int k = 0; k < 128; ++k) acc += h3[k] * w4f[(size_t)k*5 + n];
        out[b*5 + n] = acc;
    }
}

// =====================================================================
extern "C" void kernel_launch(void* const* d_in, const int* in_sizes, int n_in,
                              void* d_out, int out_size, void* d_ws, size_t ws_size,
                              hipStream_t stream)
{
    const float* X      = (const float*)d_in[0];
    const float* w1     = (const float*)d_in[1];
    const float* bn1    = (const float*)d_in[2];
    const float* w2     = (const float*)d_in[3];
    const float* bn2    = (const float*)d_in[4];
    const float* w3     = (const float*)d_in[5];
    const float* bn3    = (const float*)d_in[6];
    const float* map2w  = (const float*)d_in[7];
    const float* map2b  = (const float*)d_in[8];
    const float* bnm2   = (const float*)d_in[9];
    const float* g1w    = (const float*)d_in[10];
    const float* g1b    = (const float*)d_in[11];
    const float* bnA1   = (const float*)d_in[12];
    const float* th1w   = (const float*)d_in[13];
    const float* th1b   = (const float*)d_in[14];
    const float* bnM1   = (const float*)d_in[15];
    const float* g2w    = (const float*)d_in[16];
    const float* g2b    = (const float*)d_in[17];
    const float* bnA2   = (const float*)d_in[18];
    const float* th2w   = (const float*)d_in[19];
    const float* th2b   = (const float*)d_in[20];
    const float* bnM2   = (const float*)d_in[21];
    const float* fc1w   = (const float*)d_in[22];
    const float* fc1b   = (const float*)d_in[23];
    const float* fc2w   = (const float*)d_in[24];
    const float* fc2b   = (const float*)d_in[25];
    const float* fc3w   = (const float*)d_in[26];
    const float* fc3b   = (const float*)d_in[27];
    const float* fc4w   = (const float*)d_in[28];
    const float* fc4b   = (const float*)d_in[29];
    float* out = (float*)d_out;

    float* ws = (float*)d_ws;
    const size_t N_P2C = (size_t)192 * C2 * L2P;    // 9,265,152
    const size_t N_P3  = (size_t)768 * C3 * L3P;    // 18,776,064
    float* pool2c = ws;
    float* pool3  = ws + N_P2C;
    float* a_pe   = pool3 + N_P3;
    float* feats  = a_pe + (size_t)768 * D2;

    for (int boff = 0; boff < 768; boff += 192) {
        hipLaunchKernelGGL(k_conv12, dim3(192*24), dim3(256), 0, stream,
                           X, w1, bn1, w2, bn2, pool2c, boff);
        hipLaunchKernelGGL(k_conv3, dim3(192*12), dim3(256), 0, stream,
                           pool2c, w3, bn3, pool3, boff);
    }
    hipLaunchKernelGGL(k_map2, dim3(96), dim3(256), 0, stream,
                       pool3, map2w, map2b, bnm2, a_pe);
    hipLaunchKernelGGL(k_mpnn, dim3(160), dim3(256), 0, stream,
                       a_pe, g1w, g1b, bnA1, th1w, th1b, bnM1, feats, 5, 1, 0);
    hipLaunchKernelGGL(k_mpnn, dim3(96), dim3(256), 0, stream,
                       a_pe, g2w, g2b, bnA2, th2w, th2b, bnM2, feats, 3, 2, 2560);
    hipLaunchKernelGGL(k_fc, dim3(32), dim3(256), 0, stream,
                       feats, fc1w, fc1b, fc2w, fc2b, fc3w, fc3b, fc4w, fc4b, out);
}

// Round 2
// 2027.704 us; speedup vs baseline: 1.8910x; 1.8910x over previous
//
#include <hip/hip_runtime.h>
#include <hip/hip_bf16.h>

// ---------------- constants ----------------
#define L1X   1500   // raw sequence length
#define L1P   751    // pool1 length
#define C1    64
#define L2P   377    // pool2 length
#define C2    128
#define L3P   191    // pool3 length
#define C3    128
#define FEATK 24448  // C3*L3P
#define D2    256
#define HIDN  128

// map2 GEMM config
#define SK      32            // split-K ways
#define KCHUNK  764           // FEATK / SK = 191*4
#define NIT     191           // KCHUNK / 4

// =====================================================================
// K2: fused conv1(+bn+relu+pool) recompute  ->  conv2+bn2+relu+pool
// grid: rows_in_chunk * 24 tiles, block 256
// =====================================================================
__global__ __launch_bounds__(256)
void k_conv12(const float* __restrict__ X, const float* __restrict__ w1,
              const float* __restrict__ bn1, const float* __restrict__ w2,
              const float* __restrict__ bn2, float* __restrict__ pool2,
              int b_off)
{
    const int blk  = blockIdx.x;
    const int b    = b_off + blk / 24;
    const int i0   = (blk % 24) * 16;

    __shared__ float xrow[L1X];
    __shared__ float t1[C1 * 34];

    for (int e = threadIdx.x; e < L1X; e += 256) xrow[e] = X[(size_t)b * L1X + e];
    __syncthreads();

    // pool1 tile: t in [tb, tb+33]
    const int tb = 2 * i0 - 3;
    for (int e = threadIdx.x; e < C1 * 34; e += 256) {
        int c = e / 34, j = e - c * 34;
        int t = tb + j;
        float val = 0.f;
        if (t >= 0 && t < L1P) {
            float wk0 = w1[c*3+0], wk1 = w1[c*3+1], wk2 = w1[c*3+2];
            float s    = bn1[c] * rsqrtf(bn1[192+c] + 1e-5f);
            float bias = bn1[64+c] - bn1[128+c] * s;
            float v0 = 0.f, v1 = 0.f;
            if (t >= 1) {               // conv pos l = 2t-1  (reads x[2t-2..2t])
                int l = 2*t - 1;
                float x2 = (l+1 < L1X) ? xrow[l+1] : 0.f;
                float cv = wk0*xrow[l-1] + wk1*xrow[l] + wk2*x2;
                v0 = fmaxf(cv*s + bias, 0.f);
            }
            if (t <= 749) {             // conv pos l = 2t    (reads x[2t-1..2t+1])
                int l = 2*t;
                float x0 = (l-1 >= 0) ? xrow[l-1] : 0.f;
                float cv = wk0*x0 + wk1*xrow[l] + wk2*xrow[l+1];
                v1 = fmaxf(cv*s + bias, 0.f);
            }
            val = fmaxf(v0, v1);
        }
        t1[c*34 + j] = val;
    }
    __syncthreads();

    const int c    = threadIdx.x & 127;   // out-channel
    const int grp  = threadIdx.x >> 7;    // position group (0/1)
    const int lbase = 16 * grp;

    float acc0[8] = {0,0,0,0,0,0,0,0};
    float acc1[8] = {0,0,0,0,0,0,0,0};
    const float* Wc = w2 + c * (C1*3);

    for (int ic = 0; ic < C1; ++ic) {
        float xv[18];
        #pragma unroll
        for (int q = 0; q < 18; ++q) xv[q] = t1[ic*34 + lbase + q];
        #pragma unroll
        for (int k = 0; k < 3; ++k) {
            float w = Wc[ic*3 + k];
            #pragma unroll
            for (int j = 0; j < 8; ++j) {
                acc0[j] += w * xv[2*j + k];
                acc1[j] += w * xv[2*j + k + 1];
            }
        }
    }
    float s2 = bn2[c] * rsqrtf(bn2[384+c] + 1e-5f);
    float b2 = bn2[128+c] - bn2[256+c] * s2;
    #pragma unroll
    for (int j = 0; j < 8; ++j) {
        int i = i0 + grp*8 + j;
        if (i < L2P) {
            float v0 = (i >= 1) ? fmaxf(acc0[j]*s2 + b2, 0.f) : 0.f;
            float v1 = fmaxf(acc1[j]*s2 + b2, 0.f);
            pool2[((size_t)(b - b_off)*C2 + c)*L2P + i] = fmaxf(v0, v1);
        }
    }
}

// =====================================================================
// K3: conv3+bn3+relu+pool. grid: rows_in_chunk * 12 tiles, block 256
// =====================================================================
__global__ __launch_bounds__(256)
void k_conv3(const float* __restrict__ pool2, const float* __restrict__ w3,
             const float* __restrict__ bn3, float* __restrict__ pool3, int b_off)
{
    const int blk = blockIdx.x;
    const int bl  = blk / 12;             // local row in chunk
    const int b   = b_off + bl;           // global row
    const int i0  = (blk % 12) * 16;

    __shared__ float t2[C2 * 34];
    const int tb = 2*i0 - 4;
    for (int e = threadIdx.x; e < C2*34; e += 256) {
        int ic = e / 34, j = e - ic*34;
        int t = tb + j;
        t2[e] = (t >= 0 && t < L2P) ? pool2[((size_t)bl*C2 + ic)*L2P + t] : 0.f;
    }
    __syncthreads();

    const int c    = threadIdx.x & 127;
    const int grp  = threadIdx.x >> 7;
    const int lbase = 16 * grp;

    float acc0[8] = {0,0,0,0,0,0,0,0};
    float acc1[8] = {0,0,0,0,0,0,0,0};
    const float* Wc = w3 + c * (C2*3);

    for (int ic = 0; ic < C2; ++ic) {
        float xv[18];
        #pragma unroll
        for (int q = 0; q < 18; ++q) xv[q] = t2[ic*34 + lbase + q];
        #pragma unroll
        for (int k = 0; k < 3; ++k) {
            float w = Wc[ic*3 + k];
            #pragma unroll
            for (int j = 0; j < 8; ++j) {
                acc0[j] += w * xv[2*j + k];
                acc1[j] += w * xv[2*j + k + 1];
            }
        }
    }
    float s3 = bn3[c] * rsqrtf(bn3[384+c] + 1e-5f);
    float b3 = bn3[128+c] - bn3[256+c] * s3;
    #pragma unroll
    for (int j = 0; j < 8; ++j) {
        int i = i0 + grp*8 + j;
        if (i < L3P) {
            float v0 = (i >= 1) ? fmaxf(acc0[j]*s3 + b3, 0.f) : 0.f;
            float v1 = fmaxf(acc1[j]*s3 + b3, 0.f);
            pool3[((size_t)b*C3 + c)*L3P + i] = fmaxf(v0, v1);
        }
    }
}

// =====================================================================
// K4a: split-K GEMM partials: partial[kt] = A[768,KCHUNK@kt] @ W[.,256]
// tile 128x128, 256 threads, 8x8 per thread, Kb=4
// grid: 6 (M) * 2 (N) * 32 (K) = 384 blocks
// =====================================================================
__global__ __launch_bounds__(256)
void k_map2_gemm(const float* __restrict__ A, const float* __restrict__ W,
                 float* __restrict__ part)
{
    const int bid = blockIdx.x;
    const int kt  = bid / 12;
    const int rem = bid % 12;
    const int mt  = rem >> 1;
    const int nt  = rem & 1;

    __shared__ float At[4][128];
    __shared__ float Bt[4][128];

    const int tid = threadIdx.x;
    const int m0  = (tid & 15) * 4;       // rows m0..m0+3 and m0+64..m0+67
    const int n0  = (tid >> 4) * 8;       // cols n0..n0+7

    // fill-A mapping: row = tid>>1 (0..127), fp = tid&1 -> float2 at f0+fp*2
    const int arow = tid >> 1;
    const int afp  = tid & 1;
    // fill-B mapping: f = tid>>6 (0..3), n2 = tid&63 -> float2 at col n2*2
    const int bf   = tid >> 6;
    const int bn2c = (tid & 63) * 2;

    const float* Arow = A + (size_t)(mt * 128 + arow) * FEATK + kt * KCHUNK + afp * 2;
    const float* Brow = W + (size_t)(kt * KCHUNK + bf) * D2 + nt * 128 + bn2c;

    float acc[8][8];
    #pragma unroll
    for (int i = 0; i < 8; ++i)
        #pragma unroll
        for (int j = 0; j < 8; ++j) acc[i][j] = 0.f;

    for (int it = 0; it < NIT; ++it) {
        __syncthreads();
        {
            const float2 av = *(const float2*)(Arow + it * 4);
            At[afp*2 + 0][arow] = av.x;
            At[afp*2 + 1][arow] = av.y;
            const float2 bv = *(const float2*)(Brow + (size_t)it * 4 * D2);
            *(float2*)&Bt[bf][bn2c] = bv;
        }
        __syncthreads();

        #pragma unroll
        for (int k = 0; k < 4; ++k) {
            float4 a0 = *(const float4*)&At[k][m0];
            float4 a1 = *(const float4*)&At[k][m0 + 64];
            float4 b0 = *(const float4*)&Bt[k][n0];
            float4 b1 = *(const float4*)&Bt[k][n0 + 4];
            float av[8] = {a0.x, a0.y, a0.z, a0.w, a1.x, a1.y, a1.z, a1.w};
            float bv[8] = {b0.x, b0.y, b0.z, b0.w, b1.x, b1.y, b1.z, b1.w};
            #pragma unroll
            for (int i = 0; i < 8; ++i)
                #pragma unroll
                for (int j = 0; j < 8; ++j)
                    acc[i][j] += av[i] * bv[j];
        }
    }

    // store partial tile
    float* P = part + ((size_t)kt * 768) * D2;
    #pragma unroll
    for (int i = 0; i < 8; ++i) {
        int grow = mt * 128 + ((i < 4) ? (m0 + i) : (m0 + 64 + i - 4));
        float* dst = P + (size_t)grow * D2 + nt * 128 + n0;
        *(float4*)(dst)     = make_float4(acc[i][0], acc[i][1], acc[i][2], acc[i][3]);
        *(float4*)(dst + 4) = make_float4(acc[i][4], acc[i][5], acc[i][6], acc[i][7]);
    }
}

// =====================================================================
// K4b: reduce split-K partials + bias + BN + positional encoding
// grid 768 (one row per block), block 256 (one col per thread)
// =====================================================================
__global__ __launch_bounds__(256)
void k_map2fin(const float* __restrict__ part, const float* __restrict__ mb,
               const float* __restrict__ bn, float* __restrict__ out)
{
    const int row = blockIdx.x;
    const int n   = threadIdx.x;
    float acc = 0.f;
    #pragma unroll
    for (int kt = 0; kt < SK; ++kt)
        acc += part[((size_t)kt * 768 + row) * D2 + n];

    float s    = bn[n] * rsqrtf(bn[768+n] + 1e-5f);
    float beta = bn[256+n];
    float mu   = bn[512+n];
    float bias = mb[n];
    int   jj   = n >> 1;
    float freq = expf((float)(2*jj) * (-4.605170185988092f / 256.f)); // -ln(100)/256
    int   t    = (row >> 2) % 6;
    float ang  = (float)t * freq;
    float pe   = (n & 1) ? cosf(ang) : sinf(ang);
    out[(size_t)row*D2 + n] = (acc + bias - mu)*s + beta + pe;
}

// =====================================================================
// K5: MPNN block (win=2). one block per graph, block 256
// =====================================================================
__global__ __launch_bounds__(256)
void k_mpnn(const float* __restrict__ a_pe, const float* __restrict__ gw,
            const float* __restrict__ gb, const float* __restrict__ bnA,
            const float* __restrict__ tw, const float* __restrict__ tb_,
            const float* __restrict__ bnM, float* __restrict__ feats,
            int nw, int stride, int base)
{
    const int g  = blockIdx.x;
    const int b  = g / nw, wi = g % nw;
    const int tid = threadIdx.x;

    __shared__ float Xc[8][256];
    __shared__ float Xb[8][256];
    __shared__ float Fs[8][256];
    __shared__ float Adj[8][8];
    __shared__ float hsm[8][128];

    for (int e = tid; e < 2048; e += 256) {
        int nn = e >> 8, d = e & 255;
        int tt = nn >> 2, sn = nn & 3;
        float v = a_pe[(((size_t)(b*6) + (wi*stride + tt))*4 + sn)*D2 + d];
        Xc[nn][d] = v;
        float s = bnA[d] * rsqrtf(bnA[768+d] + 1e-5f);
        Xb[nn][d] = (v - bnA[512+d])*s + bnA[256+d];
    }
    __syncthreads();

    {   // f = Xc @ gw + gb
        const int d = tid;
        #pragma unroll
        for (int nn = 0; nn < 8; ++nn) {
            float acc = gb[d];
            for (int k = 0; k < 256; ++k) acc += Xc[nn][k] * gw[(size_t)k*D2 + d];
            Fs[nn][d] = acc;
        }
    }
    __syncthreads();

    if (tid < 64) {   // raw adjacency + diag suppress + leaky
        int nn = tid >> 3, m = tid & 7;
        float s = 0.f;
        for (int d = 0; d < 256; ++d) s += Fs[nn][d] * Fs[m][d];
        if (nn == m) s -= 1e8f;
        s = (s > 0.f) ? s : 0.01f*s;
        Adj[nn][m] = s;
    }
    __syncthreads();

    if (tid < 8) {    // softmax row + eye + decay mask
        int nn = tid;
        float mx = -1e30f;
        for (int m = 0; m < 8; ++m) mx = fmaxf(mx, Adj[nn][m]);
        float ex[8]; float sum = 0.f;
        for (int m = 0; m < 8; ++m) { ex[m] = expf(Adj[nn][m]-mx); sum += ex[m]; }
        float inv = 1.f / sum;
        for (int m = 0; m < 8; ++m) {
            float v = ex[m]*inv + ((nn==m) ? 1.f : 0.f);
            v *= ((nn>>2) == (m>>2)) ? 1.f : 0.7f;   // 0.7^|dt|, dt in {0,1}
            Adj[nn][m] = v;
        }
    }
    __syncthreads();

    {   // hmid = Adj @ Xb   (store into Fs, no longer needed)
        const int d = tid;
        float hm[8];
        #pragma unroll
        for (int nn = 0; nn < 8; ++nn) {
            float a = 0.f;
            #pragma unroll
            for (int m = 0; m < 8; ++m) a += Adj[nn][m] * Xb[m][d];
            hm[nn] = a;
        }
        #pragma unroll
        for (int nn = 0; nn < 8; ++nn) Fs[nn][d] = hm[nn];
    }
    __syncthreads();

    {   // h = leaky(BN(hmid @ tw + tb))
        const int o = tid & 127, half = tid >> 7;
        float ms  = bnM[o] * rsqrtf(bnM[384+o] + 1e-5f);
        float mbe = bnM[128+o], mmu = bnM[256+o];
        #pragma unroll
        for (int q = 0; q < 4; ++q) {
            int nn = half + 2*q;
            float acc = tb_[o];
            for (int d = 0; d < 256; ++d) acc += Fs[nn][d] * tw[(size_t)d*HIDN + o];
            float y = (acc - mmu)*ms + mbe;
            hsm[nn][o] = (y > 0.f) ? y : 0.01f*y;
        }
    }
    __syncthreads();

    for (int e = tid; e < 512; e += 256) {   // mean over window-time, write feats
        int sn = e >> 7, o = e & 127;
        feats[(size_t)b*4096 + base + (wi*4 + sn)*HIDN + o] =
            0.5f * (hsm[sn][o] + hsm[4+sn][o]);
    }
}

// =====================================================================
// K6: FC head, one block per batch row
// =====================================================================
__global__ __launch_bounds__(256)
void k_fc(const float* __restrict__ feats,
          const float* __restrict__ w1f, const float* __restrict__ b1f,
          const float* __restrict__ w2f, const float* __restrict__ b2f,
          const float* __restrict__ w3f, const float* __restrict__ b3f,
          const float* __restrict__ w4f, const float* __restrict__ b4f,
          float* __restrict__ out)
{
    const int b = blockIdx.x;
    __shared__ float row[4096];
    __shared__ float h1[256], h2[256], h3[128];
    for (int e = threadIdx.x; e < 4096; e += 256) row[e] = feats[(size_t)b*4096 + e];
    __syncthreads();
    const int n = threadIdx.x;
    {
        float acc = b1f[n];
        for (int f = 0; f < 4096; ++f) acc += row[f] * w1f[(size_t)f*256 + n];
        h1[n] = fmaxf(acc, 0.f);
    }
    __syncthreads();
    {
        float acc = b2f[n];
        for (int k = 0; k < 256; ++k) acc += h1[k] * w2f[(size_t)k*256 + n];
        h2[n] = fmaxf(acc, 0.f);
    }
    __syncthreads();
    if (n < 128) {
        float acc = b3f[n];
        for (int k = 0; k < 256; ++k) acc += h2[k] * w3f[(size_t)k*128 + n];
        h3[n] = fmaxf(acc, 0.f);
    }
    __syncthreads();
    if (n < 5) {
        float acc = b4f[n];
        for (int k = 0; k < 128; ++k) acc += h3[k] * w4f[(size_t)k*5 + n];
        out[b*5 + n] = acc;
    }
}

// =====================================================================
extern "C" void kernel_launch(void* const* d_in, const int* in_sizes, int n_in,
                              void* d_out, int out_size, void* d_ws, size_t ws_size,
                              hipStream_t stream)
{
    const float* X      = (const float*)d_in[0];
    const float* w1     = (const float*)d_in[1];
    const float* bn1    = (const float*)d_in[2];
    const float* w2     = (const float*)d_in[3];
    const float* bn2    = (const float*)d_in[4];
    const float* w3     = (const float*)d_in[5];
    const float* bn3    = (const float*)d_in[6];
    const float* map2w  = (const float*)d_in[7];
    const float* map2b  = (const float*)d_in[8];
    const float* bnm2   = (const float*)d_in[9];
    const float* g1w    = (const float*)d_in[10];
    const float* g1b    = (const float*)d_in[11];
    const float* bnA1   = (const float*)d_in[12];
    const float* th1w   = (const float*)d_in[13];
    const float* th1b   = (const float*)d_in[14];
    const float* bnM1   = (const float*)d_in[15];
    const float* g2w    = (const float*)d_in[16];
    const float* g2b    = (const float*)d_in[17];
    const float* bnA2   = (const float*)d_in[18];
    const float* th2w   = (const float*)d_in[19];
    const float* th2b   = (const float*)d_in[20];
    const float* bnM2   = (const float*)d_in[21];
    const float* fc1w   = (const float*)d_in[22];
    const float* fc1b   = (const float*)d_in[23];
    const float* fc2w   = (const float*)d_in[24];
    const float* fc2b   = (const float*)d_in[25];
    const float* fc3w   = (const float*)d_in[26];
    const float* fc3b   = (const float*)d_in[27];
    const float* fc4w   = (const float*)d_in[28];
    const float* fc4b   = (const float*)d_in[29];
    float* out = (float*)d_out;

    float* ws = (float*)d_ws;
    const size_t N_P2C = (size_t)192 * C2 * L2P;    // 9,265,152 floats (37 MB)
    const size_t N_P3  = (size_t)768 * C3 * L3P;    // 18,776,064 floats (75 MB)
    float* pool2c = ws;
    float* pool3  = ws + N_P2C;
    float* a_pe   = pool3 + N_P3;
    float* feats  = a_pe + (size_t)768 * D2;
    // split-K partials alias pool2c (free after conv loop): 32*768*256 = 6.29M < 9.27M floats
    float* part   = ws;

    for (int boff = 0; boff < 768; boff += 192) {
        hipLaunchKernelGGL(k_conv12, dim3(192*24), dim3(256), 0, stream,
                           X, w1, bn1, w2, bn2, pool2c, boff);
        hipLaunchKernelGGL(k_conv3, dim3(192*12), dim3(256), 0, stream,
                           pool2c, w3, bn3, pool3, boff);
    }
    hipLaunchKernelGGL(k_map2_gemm, dim3(384), dim3(256), 0, stream,
                       pool3, map2w, part);
    hipLaunchKernelGGL(k_map2fin, dim3(768), dim3(256), 0, stream,
                       part, map2b, bnm2, a_pe);
    hipLaunchKernelGGL(k_mpnn, dim3(160), dim3(256), 0, stream,
                       a_pe, g1w, g1b, bnA1, th1w, th1b, bnM1, feats, 5, 1, 0);
    hipLaunchKernelGGL(k_mpnn, dim3(96), dim3(256), 0, stream,
                       a_pe, g2w, g2b, bnA2, th2w, th2b, bnM2, feats, 3, 2, 2560);
    hipLaunchKernelGGL(k_fc, dim3(32), dim3(256), 0, stream,
                       feats, fc1w, fc1b, fc2w, fc2b, fc3w, fc3b, fc4w, fc4b, out);
}

// Round 3
// 1856.449 us; speedup vs baseline: 2.0654x; 1.0922x over previous
//
#include <hip/hip_runtime.h>
#include <hip/hip_bf16.h>

// ---------------- constants ----------------
#define L1X   1500   // raw sequence length
#define L1P   751    // pool1 length
#define C1    64
#define L2P   377    // pool2 length
#define C2    128
#define L3P   191    // pool3 length
#define C3    128
#define FEATK 24448  // C3*L3P
#define D2    256
#define HIDN  128

// map2 GEMM config
#define SK      32            // split-K ways
#define KCHUNK  764           // FEATK / SK = 191*4
#define NIT     191           // KCHUNK / 4

#define TSTR  36              // padded LDS tile stride (36 floats = 144B, 16B-aligned rows)

// =====================================================================
// K2: fused conv1(+bn+relu+pool) recompute  ->  conv2+bn2+relu+pool
// grid: rows_in_chunk * 24 tiles, block 256
// =====================================================================
__global__ __launch_bounds__(256)
void k_conv12(const float* __restrict__ X, const float* __restrict__ w1,
              const float* __restrict__ bn1, const float* __restrict__ w2,
              const float* __restrict__ bn2, float* __restrict__ pool2,
              int b_off)
{
    const int blk  = blockIdx.x;
    const int b    = b_off + blk / 24;
    const int i0   = (blk % 24) * 16;

    __shared__ __align__(16) float xrow[L1X];
    __shared__ __align__(16) float t1[C1 * TSTR];

    for (int e = threadIdx.x; e < L1X; e += 256) xrow[e] = X[(size_t)b * L1X + e];
    __syncthreads();

    // pool1 tile: t in [tb, tb+33]
    const int tb = 2 * i0 - 3;
    for (int e = threadIdx.x; e < C1 * 34; e += 256) {
        int c = e / 34, j = e - c * 34;
        int t = tb + j;
        float val = 0.f;
        if (t >= 0 && t < L1P) {
            float wk0 = w1[c*3+0], wk1 = w1[c*3+1], wk2 = w1[c*3+2];
            float s    = bn1[c] * rsqrtf(bn1[192+c] + 1e-5f);
            float bias = bn1[64+c] - bn1[128+c] * s;
            float v0 = 0.f, v1 = 0.f;
            if (t >= 1) {               // conv pos l = 2t-1  (reads x[2t-2..2t])
                int l = 2*t - 1;
                float x2 = (l+1 < L1X) ? xrow[l+1] : 0.f;
                float cv = wk0*xrow[l-1] + wk1*xrow[l] + wk2*x2;
                v0 = fmaxf(cv*s + bias, 0.f);
            }
            if (t <= 749) {             // conv pos l = 2t    (reads x[2t-1..2t+1])
                int l = 2*t;
                float x0 = (l-1 >= 0) ? xrow[l-1] : 0.f;
                float cv = wk0*x0 + wk1*xrow[l] + wk2*xrow[l+1];
                v1 = fmaxf(cv*s + bias, 0.f);
            }
            val = fmaxf(v0, v1);
        }
        t1[c*TSTR + j] = val;
    }
    __syncthreads();

    const int c    = threadIdx.x & 127;   // out-channel
    const int grp  = threadIdx.x >> 7;    // position group (0/1)
    const int lbase = 16 * grp;

    float acc0[8] = {0,0,0,0,0,0,0,0};
    float acc1[8] = {0,0,0,0,0,0,0,0};
    const float* Wc = w2 + c * (C1*3);

    for (int icg = 0; icg < C1; icg += 4) {
        // 12 contiguous weights = 4 input channels x 3 taps
        float4 wA = *(const float4*)(Wc + icg*3);
        float4 wB = *(const float4*)(Wc + icg*3 + 4);
        float4 wC = *(const float4*)(Wc + icg*3 + 8);
        float w[4][3] = {{wA.x,wA.y,wA.z},{wA.w,wB.x,wB.y},
                         {wB.z,wB.w,wC.x},{wC.y,wC.z,wC.w}};
        #pragma unroll
        for (int s = 0; s < 4; ++s) {
            const float* rowp = &t1[(icg + s)*TSTR + lbase];
            float4 x0 = *(const float4*)(rowp);
            float4 x1 = *(const float4*)(rowp + 4);
            float4 x2 = *(const float4*)(rowp + 8);
            float4 x3 = *(const float4*)(rowp + 12);
            float2 x4 = *(const float2*)(rowp + 16);
            float xv[18] = {x0.x,x0.y,x0.z,x0.w, x1.x,x1.y,x1.z,x1.w,
                            x2.x,x2.y,x2.z,x2.w, x3.x,x3.y,x3.z,x3.w,
                            x4.x,x4.y};
            #pragma unroll
            for (int k = 0; k < 3; ++k) {
                float wv = w[s][k];
                #pragma unroll
                for (int j = 0; j < 8; ++j) {
                    acc0[j] += wv * xv[2*j + k];
                    acc1[j] += wv * xv[2*j + k + 1];
                }
            }
        }
    }
    float s2 = bn2[c] * rsqrtf(bn2[384+c] + 1e-5f);
    float b2 = bn2[128+c] - bn2[256+c] * s2;
    #pragma unroll
    for (int j = 0; j < 8; ++j) {
        int i = i0 + grp*8 + j;
        if (i < L2P) {
            float v0 = (i >= 1) ? fmaxf(acc0[j]*s2 + b2, 0.f) : 0.f;
            float v1 = fmaxf(acc1[j]*s2 + b2, 0.f);
            pool2[((size_t)(b - b_off)*C2 + c)*L2P + i] = fmaxf(v0, v1);
        }
    }
}

// =====================================================================
// K3: conv3+bn3+relu+pool. grid: rows_in_chunk * 12 tiles, block 256
// =====================================================================
__global__ __launch_bounds__(256)
void k_conv3(const float* __restrict__ pool2, const float* __restrict__ w3,
             const float* __restrict__ bn3, float* __restrict__ pool3, int b_off)
{
    const int blk = blockIdx.x;
    const int bl  = blk / 12;             // local row in chunk
    const int b   = b_off + bl;           // global row
    const int i0  = (blk % 12) * 16;

    __shared__ __align__(16) float t2[C2 * TSTR];
    const int tb = 2*i0 - 4;
    for (int e = threadIdx.x; e < C2*34; e += 256) {
        int ic = e / 34, j = e - ic*34;
        int t = tb + j;
        t2[ic*TSTR + j] = (t >= 0 && t < L2P) ? pool2[((size_t)bl*C2 + ic)*L2P + t] : 0.f;
    }
    __syncthreads();

    const int c    = threadIdx.x & 127;
    const int grp  = threadIdx.x >> 7;
    const int lbase = 16 * grp;

    float acc0[8] = {0,0,0,0,0,0,0,0};
    float acc1[8] = {0,0,0,0,0,0,0,0};
    const float* Wc = w3 + c * (C2*3);

    for (int icg = 0; icg < C2; icg += 4) {
        float4 wA = *(const float4*)(Wc + icg*3);
        float4 wB = *(const float4*)(Wc + icg*3 + 4);
        float4 wC = *(const float4*)(Wc + icg*3 + 8);
        float w[4][3] = {{wA.x,wA.y,wA.z},{wA.w,wB.x,wB.y},
                         {wB.z,wB.w,wC.x},{wC.y,wC.z,wC.w}};
        #pragma unroll
        for (int s = 0; s < 4; ++s) {
            const float* rowp = &t2[(icg + s)*TSTR + lbase];
            float4 x0 = *(const float4*)(rowp);
            float4 x1 = *(const float4*)(rowp + 4);
            float4 x2 = *(const float4*)(rowp + 8);
            float4 x3 = *(const float4*)(rowp + 12);
            float2 x4 = *(const float2*)(rowp + 16);
            float xv[18] = {x0.x,x0.y,x0.z,x0.w, x1.x,x1.y,x1.z,x1.w,
                            x2.x,x2.y,x2.z,x2.w, x3.x,x3.y,x3.z,x3.w,
                            x4.x,x4.y};
            #pragma unroll
            for (int k = 0; k < 3; ++k) {
                float wv = w[s][k];
                #pragma unroll
                for (int j = 0; j < 8; ++j) {
                    acc0[j] += wv * xv[2*j + k];
                    acc1[j] += wv * xv[2*j + k + 1];
                }
            }
        }
    }
    float s3 = bn3[c] * rsqrtf(bn3[384+c] + 1e-5f);
    float b3 = bn3[128+c] - bn3[256+c] * s3;
    #pragma unroll
    for (int j = 0; j < 8; ++j) {
        int i = i0 + grp*8 + j;
        if (i < L3P) {
            float v0 = (i >= 1) ? fmaxf(acc0[j]*s3 + b3, 0.f) : 0.f;
            float v1 = fmaxf(acc1[j]*s3 + b3, 0.f);
            pool3[((size_t)b*C3 + c)*L3P + i] = fmaxf(v0, v1);
        }
    }
}

// =====================================================================
// K4a: split-K GEMM partials: partial[kt] = A[768,KCHUNK@kt] @ W[.,256]
// tile 128x128, 256 threads, 8x8 per thread, Kb=4
// grid: 6 (M) * 2 (N) * 32 (K) = 384 blocks
// =====================================================================
__global__ __launch_bounds__(256)
void k_map2_gemm(const float* __restrict__ A, const float* __restrict__ W,
                 float* __restrict__ part)
{
    const int bid = blockIdx.x;
    const int kt  = bid / 12;
    const int rem = bid % 12;
    const int mt  = rem >> 1;
    const int nt  = rem & 1;

    __shared__ float At[4][128];
    __shared__ float Bt[4][128];

    const int tid = threadIdx.x;
    const int m0  = (tid & 15) * 4;       // rows m0..m0+3 and m0+64..m0+67
    const int n0  = (tid >> 4) * 8;       // cols n0..n0+7

    // fill-A mapping: row = tid>>1 (0..127), fp = tid&1 -> float2 at f0+fp*2
    const int arow = tid >> 1;
    const int afp  = tid & 1;
    // fill-B mapping: f = tid>>6 (0..3), n2 = tid&63 -> float2 at col n2*2
    const int bf   = tid >> 6;
    const int bn2c = (tid & 63) * 2;

    const float* Arow = A + (size_t)(mt * 128 + arow) * FEATK + kt * KCHUNK + afp * 2;
    const float* Brow = W + (size_t)(kt * KCHUNK + bf) * D2 + nt * 128 + bn2c;

    float acc[8][8];
    #pragma unroll
    for (int i = 0; i < 8; ++i)
        #pragma unroll
        for (int j = 0; j < 8; ++j) acc[i][j] = 0.f;

    for (int it = 0; it < NIT; ++it) {
        __syncthreads();
        {
            const float2 av = *(const float2*)(Arow + it * 4);
            At[afp*2 + 0][arow] = av.x;
            At[afp*2 + 1][arow] = av.y;
            const float2 bv = *(const float2*)(Brow + (size_t)it * 4 * D2);
            *(float2*)&Bt[bf][bn2c] = bv;
        }
        __syncthreads();

        #pragma unroll
        for (int k = 0; k < 4; ++k) {
            float4 a0 = *(const float4*)&At[k][m0];
            float4 a1 = *(const float4*)&At[k][m0 + 64];
            float4 b0 = *(const float4*)&Bt[k][n0];
            float4 b1 = *(const float4*)&Bt[k][n0 + 4];
            float av[8] = {a0.x, a0.y, a0.z, a0.w, a1.x, a1.y, a1.z, a1.w};
            float bv[8] = {b0.x, b0.y, b0.z, b0.w, b1.x, b1.y, b1.z, b1.w};
            #pragma unroll
            for (int i = 0; i < 8; ++i)
                #pragma unroll
                for (int j = 0; j < 8; ++j)
                    acc[i][j] += av[i] * bv[j];
        }
    }

    // store partial tile
    float* P = part + ((size_t)kt * 768) * D2;
    #pragma unroll
    for (int i = 0; i < 8; ++i) {
        int grow = mt * 128 + ((i < 4) ? (m0 + i) : (m0 + 64 + i - 4));
        float* dst = P + (size_t)grow * D2 + nt * 128 + n0;
        *(float4*)(dst)     = make_float4(acc[i][0], acc[i][1], acc[i][2], acc[i][3]);
        *(float4*)(dst + 4) = make_float4(acc[i][4], acc[i][5], acc[i][6], acc[i][7]);
    }
}

// =====================================================================
// K4b: reduce split-K partials + bias + BN + positional encoding
// grid 768 (one row per block), block 256 (one col per thread)
// =====================================================================
__global__ __launch_bounds__(256)
void k_map2fin(const float* __restrict__ part, const float* __restrict__ mb,
               const float* __restrict__ bn, float* __restrict__ out)
{
    const int row = blockIdx.x;
    const int n   = threadIdx.x;
    float acc = 0.f;
    #pragma unroll
    for (int kt = 0; kt < SK; ++kt)
        acc += part[((size_t)kt * 768 + row) * D2 + n];

    float s    = bn[n] * rsqrtf(bn[768+n] + 1e-5f);
    float beta = bn[256+n];
    float mu   = bn[512+n];
    float bias = mb[n];
    int   jj   = n >> 1;
    float freq = expf((float)(2*jj) * (-4.605170185988092f / 256.f)); // -ln(100)/256
    int   t    = (row >> 2) % 6;
    float ang  = (float)t * freq;
    float pe   = (n & 1) ? cosf(ang) : sinf(ang);
    out[(size_t)row*D2 + n] = (acc + bias - mu)*s + beta + pe;
}

// =====================================================================
// K5: MPNN block (win=2). one block per graph, block 256
// =====================================================================
__global__ __launch_bounds__(256)
void k_mpnn(const float* __restrict__ a_pe, const float* __restrict__ gw,
            const float* __restrict__ gb, const float* __restrict__ bnA,
            const float* __restrict__ tw, const float* __restrict__ tb_,
            const float* __restrict__ bnM, float* __restrict__ feats,
            int nw, int stride, int base)
{
    const int g  = blockIdx.x;
    const int b  = g / nw, wi = g % nw;
    const int tid = threadIdx.x;

    __shared__ float Xc[8][256];
    __shared__ float Xb[8][256];
    __shared__ float Fs[8][256];
    __shared__ float Adj[8][8];
    __shared__ float hsm[8][128];

    for (int e = tid; e < 2048; e += 256) {
        int nn = e >> 8, d = e & 255;
        int tt = nn >> 2, sn = nn & 3;
        float v = a_pe[(((size_t)(b*6) + (wi*stride + tt))*4 + sn)*D2 + d];
        Xc[nn][d] = v;
        float s = bnA[d] * rsqrtf(bnA[768+d] + 1e-5f);
        Xb[nn][d] = (v - bnA[512+d])*s + bnA[256+d];
    }
    __syncthreads();

    {   // f = Xc @ gw + gb
        const int d = tid;
        #pragma unroll
        for (int nn = 0; nn < 8; ++nn) {
            float acc = gb[d];
            for (int k = 0; k < 256; ++k) acc += Xc[nn][k] * gw[(size_t)k*D2 + d];
            Fs[nn][d] = acc;
        }
    }
    __syncthreads();

    if (tid < 64) {   // raw adjacency + diag suppress + leaky
        int nn = tid >> 3, m = tid & 7;
        float s = 0.f;
        for (int d = 0; d < 256; ++d) s += Fs[nn][d] * Fs[m][d];
        if (nn == m) s -= 1e8f;
        s = (s > 0.f) ? s : 0.01f*s;
        Adj[nn][m] = s;
    }
    __syncthreads();

    if (tid < 8) {    // softmax row + eye + decay mask
        int nn = tid;
        float mx = -1e30f;
        for (int m = 0; m < 8; ++m) mx = fmaxf(mx, Adj[nn][m]);
        float ex[8]; float sum = 0.f;
        for (int m = 0; m < 8; ++m) { ex[m] = expf(Adj[nn][m]-mx); sum += ex[m]; }
        float inv = 1.f / sum;
        for (int m = 0; m < 8; ++m) {
            float v = ex[m]*inv + ((nn==m) ? 1.f : 0.f);
            v *= ((nn>>2) == (m>>2)) ? 1.f : 0.7f;   // 0.7^|dt|, dt in {0,1}
            Adj[nn][m] = v;
        }
    }
    __syncthreads();

    {   // hmid = Adj @ Xb   (store into Fs, no longer needed)
        const int d = tid;
        float hm[8];
        #pragma unroll
        for (int nn = 0; nn < 8; ++nn) {
            float a = 0.f;
            #pragma unroll
            for (int m = 0; m < 8; ++m) a += Adj[nn][m] * Xb[m][d];
            hm[nn] = a;
        }
        #pragma unroll
        for (int nn = 0; nn < 8; ++nn) Fs[nn][d] = hm[nn];
    }
    __syncthreads();

    {   // h = leaky(BN(hmid @ tw + tb))
        const int o = tid & 127, half = tid >> 7;
        float ms  = bnM[o] * rsqrtf(bnM[384+o] + 1e-5f);
        float mbe = bnM[128+o], mmu = bnM[256+o];
        #pragma unroll
        for (int q = 0; q < 4; ++q) {
            int nn = half + 2*q;
            float acc = tb_[o];
            for (int d = 0; d < 256; ++d) acc += Fs[nn][d] * tw[(size_t)d*HIDN + o];
            float y = (acc - mmu)*ms + mbe;
            hsm[nn][o] = (y > 0.f) ? y : 0.01f*y;
        }
    }
    __syncthreads();

    for (int e = tid; e < 512; e += 256) {   // mean over window-time, write feats
        int sn = e >> 7, o = e & 127;
        feats[(size_t)b*4096 + base + (wi*4 + sn)*HIDN + o] =
            0.5f * (hsm[sn][o] + hsm[4+sn][o]);
    }
}

// =====================================================================
// K6: FC head, one block per batch row
// =====================================================================
__global__ __launch_bounds__(256)
void k_fc(const float* __restrict__ feats,
          const float* __restrict__ w1f, const float* __restrict__ b1f,
          const float* __restrict__ w2f, const float* __restrict__ b2f,
          const float* __restrict__ w3f, const float* __restrict__ b3f,
          const float* __restrict__ w4f, const float* __restrict__ b4f,
          float* __restrict__ out)
{
    const int b = blockIdx.x;
    __shared__ float row[4096];
    __shared__ float h1[256], h2[256], h3[128];
    for (int e = threadIdx.x; e < 4096; e += 256) row[e] = feats[(size_t)b*4096 + e];
    __syncthreads();
    const int n = threadIdx.x;
    {
        float acc = b1f[n];
        for (int f = 0; f < 4096; ++f) acc += row[f] * w1f[(size_t)f*256 + n];
        h1[n] = fmaxf(acc, 0.f);
    }
    __syncthreads();
    {
        float acc = b2f[n];
        for (int k = 0; k < 256; ++k) acc += h1[k] * w2f[(size_t)k*256 + n];
        h2[n] = fmaxf(acc, 0.f);
    }
    __syncthreads();
    if (n < 128) {
        float acc = b3f[n];
        for (int k = 0; k < 256; ++k) acc += h2[k] * w3f[(size_t)k*128 + n];
        h3[n] = fmaxf(acc, 0.f);
    }
    __syncthreads();
    if (n < 5) {
        float acc = b4f[n];
        for (int k = 0; k < 128; ++k) acc += h3[k] * w4f[(size_t)k*5 + n];
        out[b*5 + n] = acc;
    }
}

// =====================================================================
extern "C" void kernel_launch(void* const* d_in, const int* in_sizes, int n_in,
                              void* d_out, int out_size, void* d_ws, size_t ws_size,
                              hipStream_t stream)
{
    const float* X      = (const float*)d_in[0];
    const float* w1     = (const float*)d_in[1];
    const float* bn1    = (const float*)d_in[2];
    const float* w2     = (const float*)d_in[3];
    const float* bn2    = (const float*)d_in[4];
    const float* w3     = (const float*)d_in[5];
    const float* bn3    = (const float*)d_in[6];
    const float* map2w  = (const float*)d_in[7];
    const float* map2b  = (const float*)d_in[8];
    const float* bnm2   = (const float*)d_in[9];
    const float* g1w    = (const float*)d_in[10];
    const float* g1b    = (const float*)d_in[11];
    const float* bnA1   = (const float*)d_in[12];
    const float* th1w   = (const float*)d_in[13];
    const float* th1b   = (const float*)d_in[14];
    const float* bnM1   = (const float*)d_in[15];
    const float* g2w    = (const float*)d_in[16];
    const float* g2b    = (const float*)d_in[17];
    const float* bnA2   = (const float*)d_in[18];
    const float* th2w   = (const float*)d_in[19];
    const float* th2b   = (const float*)d_in[20];
    const float* bnM2   = (const float*)d_in[21];
    const float* fc1w   = (const float*)d_in[22];
    const float* fc1b   = (const float*)d_in[23];
    const float* fc2w   = (const float*)d_in[24];
    const float* fc2b   = (const float*)d_in[25];
    const float* fc3w   = (const float*)d_in[26];
    const float* fc3b   = (const float*)d_in[27];
    const float* fc4w   = (const float*)d_in[28];
    const float* fc4b   = (const float*)d_in[29];
    float* out = (float*)d_out;

    float* ws = (float*)d_ws;
    const size_t N_P2C = (size_t)192 * C2 * L2P;    // 9,265,152 floats (37 MB)
    const size_t N_P3  = (size_t)768 * C3 * L3P;    // 18,776,064 floats (75 MB)
    float* pool2c = ws;
    float* pool3  = ws + N_P2C;
    float* a_pe   = pool3 + N_P3;
    float* feats  = a_pe + (size_t)768 * D2;
    // split-K partials alias pool2c (free after conv loop): 32*768*256 = 6.29M < 9.27M floats
    float* part   = ws;

    for (int boff = 0; boff < 768; boff += 192) {
        hipLaunchKernelGGL(k_conv12, dim3(192*24), dim3(256), 0, stream,
                           X, w1, bn1, w2, bn2, pool2c, boff);
        hipLaunchKernelGGL(k_conv3, dim3(192*12), dim3(256), 0, stream,
                           pool2c, w3, bn3, pool3, boff);
    }
    hipLaunchKernelGGL(k_map2_gemm, dim3(384), dim3(256), 0, stream,
                       pool3, map2w, part);
    hipLaunchKernelGGL(k_map2fin, dim3(768), dim3(256), 0, stream,
                       part, map2b, bnm2, a_pe);
    hipLaunchKernelGGL(k_mpnn, dim3(160), dim3(256), 0, stream,
                       a_pe, g1w, g1b, bnA1, th1w, th1b, bnM1, feats, 5, 1, 0);
    hipLaunchKernelGGL(k_mpnn, dim3(96), dim3(256), 0, stream,
                       a_pe, g2w, g2b, bnA2, th2w, th2b, bnM2, feats, 3, 2, 2560);
    hipLaunchKernelGGL(k_fc, dim3(32), dim3(256), 0, stream,
                       feats, fc1w, fc1b, fc2w, fc2b, fc3w, fc3b, fc4w, fc4b, out);
}